// Round 10
// baseline (33927.353 us; speedup 1.0000x reference)
//
#include <hip/hip_runtime.h>
#include <stdint.h>

// TinyRNN: 2-layer tanh RNN. B=64, T=2048, I=H=512.
// Phase 1: bulk GEMM preact0 = x @ Wih0 (hi/lo bf16 3-pass), stored f32 in d_out
//          (slot [b,t,:] holds preact0(t) until consumed; B overwrites with h1(t)).
// Phase 2: persistent 32 blocks (16 A + 16 B), per-iter flag sync AT LOOP TOP.
//   A iter k: h0(k) = tanh(preact0(k) + h0(k-1)@Whh0 + b0); waits {A>=k, B>=k-2}.
//   B iter k: h1(k-1) = tanh(h0(k-1)@Wih1 + h1(k-2)@Whh1 + b1); waits {all>=k}.
// SYNC: ALL inter-block state (flags, h0, h1) uses system-scope relaxed ops
// (sc0 sc1 -> bypass L1+L2, served by MALL = the coherent point). ZERO cache
// maintenance: round-7's 12.8us/iter was agent-RELEASE buffer_wbl2 + acquire
// buffer_inv per block per iter (64 L2-wide ops/iter; WRITE_SIZE showed all h
// writes hitting HBM). Writer drains vmcnt then stores flag; readers poll
// fresh MALL data directly.
// PRECISION: hi+lo bf16 split of h/x/W, 3 MFMA passes (passed, absmax 3.9e-3).

#define BDIM 64
#define TDIM 2048
#define IDIM 512
#define HDIM 512

#define NBLK 32
#define NA   16
#define CPB  32              // output cols per block (2 MFMA col-tiles)
#define BH   (BDIM * HDIM)   // 32768 elems
#define SLOT (2 * BH)        // h slot: [hi BH | lo BH]

typedef float f32x4 __attribute__((ext_vector_type(4)));
typedef __bf16 bf16x8 __attribute__((ext_vector_type(8)));

__device__ __forceinline__ float fast_tanh(float z) {
    float e = __expf(2.0f * z);
    return 1.0f - 2.0f / (e + 1.0f);
}

// 16B h-fragment load as 2x u64 system-relaxed atomics (sc0 sc1: bypass L1/L2,
// read MALL). Compiler-tracked -> automatic waitcnt before use.
__device__ __forceinline__ bf16x8 ldsys16(const __bf16* p) {
    union { unsigned long long q[2]; bf16x8 v; } u;
    u.q[0] = __hip_atomic_load((const unsigned long long*)p, __ATOMIC_RELAXED,
                               __HIP_MEMORY_SCOPE_SYSTEM);
    u.q[1] = __hip_atomic_load(((const unsigned long long*)p) + 1, __ATOMIC_RELAXED,
                               __HIP_MEMORY_SCOPE_SYSTEM);
    return u.v;
}

// 2B bf16 store, write-through to MALL (sc0 sc1). Untracked by compiler ->
// arrive path issues an explicit s_waitcnt vmcnt(0) before the barrier.
__device__ __forceinline__ void stsys_bf16(__bf16* p, float f) {
    union { __bf16 h; unsigned short s; } c; c.h = (__bf16)f;
    unsigned int bits = c.s;
    asm volatile("global_store_short %0, %1, off sc0 sc1" :: "v"(p), "v"(bits));
}

// ======================= Phase 1: preact0 = x @ Wih0 =======================
__global__ __launch_bounds__(256, 2) void xw0_gemm(
    const float* __restrict__ x, const float* __restrict__ wih0,
    float* __restrict__ pre) {
    const int nt = blockIdx.x & 15;
    const int mt = blockIdx.x >> 4;
    const int c0 = nt * 32;
    const int tx = threadIdx.x, lane = tx & 63, wv = tx >> 6;

    __shared__ __bf16 WH[16 * 2 * 64 * 8];   // 32 KB
    __shared__ __bf16 WL[16 * 2 * 64 * 8];   // 32 KB
    for (int e = tx; e < 16 * 2 * 64; e += 256) {
        int kk = e >> 7, t = (e >> 6) & 1, l = e & 63;
        int kbase = kk * 32 + ((l >> 4) << 3);
        int col = c0 + t * 16 + (l & 15);
        bf16x8 vh, vl;
#pragma unroll
        for (int j = 0; j < 8; ++j) {
            float w = wih0[(size_t)(kbase + j) * HDIM + col];
            __bf16 hi = (__bf16)w;
            vh[j] = hi; vl[j] = (__bf16)(w - (float)hi);
        }
        *reinterpret_cast<bf16x8*>(&WH[e * 8]) = vh;
        *reinterpret_cast<bf16x8*>(&WL[e * 8]) = vl;
    }
    __syncthreads();

    const int kfo = (lane >> 4) << 3;
    const int rbase = mt * 256 + wv * 64;
    const int rA = lane & 15;
    f32x4 acc[4][2];
#pragma unroll
    for (int rt = 0; rt < 4; ++rt) {
        acc[rt][0] = {0.f, 0.f, 0.f, 0.f};
        acc[rt][1] = {0.f, 0.f, 0.f, 0.f};
    }
#pragma unroll 2
    for (int kk = 0; kk < 16; ++kk) {
        bf16x8 w0h = *reinterpret_cast<const bf16x8*>(&WH[((kk * 2 + 0) * 64 + lane) * 8]);
        bf16x8 w1h = *reinterpret_cast<const bf16x8*>(&WH[((kk * 2 + 1) * 64 + lane) * 8]);
        bf16x8 w0l = *reinterpret_cast<const bf16x8*>(&WL[((kk * 2 + 0) * 64 + lane) * 8]);
        bf16x8 w1l = *reinterpret_cast<const bf16x8*>(&WL[((kk * 2 + 1) * 64 + lane) * 8]);
#pragma unroll
        for (int rt = 0; rt < 4; ++rt) {
            const float* xr = x + (size_t)(rbase + rt * 16 + rA) * IDIM + kk * 32 + kfo;
            f32x4 l4 = *reinterpret_cast<const f32x4*>(xr);
            f32x4 h4 = *reinterpret_cast<const f32x4*>(xr + 4);
            bf16x8 xh, xl;
#pragma unroll
            for (int j = 0; j < 4; ++j) {
                __bf16 a = (__bf16)l4[j]; xh[j] = a;     xl[j] = (__bf16)(l4[j] - (float)a);
                __bf16 b = (__bf16)h4[j]; xh[4 + j] = b; xl[4 + j] = (__bf16)(h4[j] - (float)b);
            }
            acc[rt][0] = __builtin_amdgcn_mfma_f32_16x16x32_bf16(xh, w0h, acc[rt][0], 0, 0, 0);
            acc[rt][1] = __builtin_amdgcn_mfma_f32_16x16x32_bf16(xh, w1h, acc[rt][1], 0, 0, 0);
            acc[rt][0] = __builtin_amdgcn_mfma_f32_16x16x32_bf16(xl, w0h, acc[rt][0], 0, 0, 0);
            acc[rt][1] = __builtin_amdgcn_mfma_f32_16x16x32_bf16(xl, w1h, acc[rt][1], 0, 0, 0);
            acc[rt][0] = __builtin_amdgcn_mfma_f32_16x16x32_bf16(xh, w0l, acc[rt][0], 0, 0, 0);
            acc[rt][1] = __builtin_amdgcn_mfma_f32_16x16x32_bf16(xh, w1l, acc[rt][1], 0, 0, 0);
        }
    }
    const int rowOff = (lane >> 4) << 2, colL = lane & 15;
#pragma unroll
    for (int rt = 0; rt < 4; ++rt)
#pragma unroll
        for (int ct = 0; ct < 2; ++ct)
#pragma unroll
            for (int m = 0; m < 4; ++m)
                __builtin_nontemporal_store(acc[rt][ct][m],
                    &pre[(size_t)(rbase + rt * 16 + rowOff + m) * HDIM + c0 + ct * 16 + colL]);
}

// ======================= Phase 2: persistent recurrence =======================
__global__ __launch_bounds__(256, 1) void rnn_persistent(
    const float* __restrict__ whh0,
    const float* __restrict__ bih0, const float* __restrict__ bhh0,
    const float* __restrict__ wih1, const float* __restrict__ whh1,
    const float* __restrict__ bih1, const float* __restrict__ bhh1,
    float* out, unsigned char* __restrict__ ws) {

    unsigned* flags = (unsigned*)ws;                         // flag i at [i*32] (128 B apart)
    __bf16* h0base  = (__bf16*)(ws + 4096);                  // 4 slots x SLOT
    __bf16* h1base  = (__bf16*)(ws + 4096 + 4 * (size_t)SLOT * 2);  // 2 slots

    const int blk  = blockIdx.x;
    const bool isA = (blk < NA);
    const int c0   = (isA ? blk : blk - NA) * CPB;
    const int tx   = threadIdx.x;
    const int lane = tx & 63;
    const int wv   = tx >> 6;
    const int r0   = wv * 16;

    // A stages Whh0 (kk 0..15); B stages Wih1 (kk 0..15) + Whh1 (kk 16..31).
    __shared__ __bf16 WH[32 * 2 * 64 * 8];  // 64 KB
    __shared__ __bf16 WL[32 * 2 * 64 * 8];  // 64 KB
    {
        const int ne = (isA ? 16 : 32) * 2 * 64;
        const float* W1 = isA ? whh0 : wih1;
        for (int e = tx; e < ne; e += 256) {
            int kk = e >> 7, t = (e >> 6) & 1, l = e & 63;
            int kbase = kk * 32 + ((l >> 4) << 3);
            int col = c0 + t * 16 + (l & 15);
            bf16x8 vh, vl;
#pragma unroll
            for (int j = 0; j < 8; ++j) {
                int kidx = kbase + j;
                float w = (kidx < 512) ? W1[(size_t)kidx * HDIM + col]
                                       : whh1[(size_t)(kidx - 512) * HDIM + col];
                __bf16 hi = (__bf16)w;
                vh[j] = hi; vl[j] = (__bf16)(w - (float)hi);
            }
            *reinterpret_cast<bf16x8*>(&WH[e * 8]) = vh;
            *reinterpret_cast<bf16x8*>(&WL[e * 8]) = vl;
        }
    }
    const int colD = c0 + (lane & 15);
    const int rowD = r0 + ((lane >> 4) << 2);
    const int rA   = r0 + (lane & 15);
    const int kfo  = (lane >> 4) << 3;
    const float bias0 = isA ? (bih0[colD] + bhh0[colD]) : (bih1[colD] + bhh1[colD]);
    const float bias1 = isA ? (bih0[colD + 16] + bhh0[colD + 16])
                            : (bih1[colD + 16] + bhh1[colD + 16]);
    __syncthreads();

    // 3-pass GEMM half (hi@Whi + lo@Whi + hi@Wlo); h frags via system loads.
    auto hhalf_mfma = [&](const __bf16* hi_row, const __bf16* lo_row, int koff,
                          f32x4& a0, f32x4& a1) {
        bf16x8 fh[16], fl[16];
#pragma unroll
        for (int kk = 0; kk < 16; ++kk) fh[kk] = ldsys16(hi_row + kk * 32 + kfo);
#pragma unroll
        for (int kk = 0; kk < 16; ++kk) fl[kk] = ldsys16(lo_row + kk * 32 + kfo);
#pragma unroll
        for (int kk = 0; kk < 16; ++kk) {
            bf16x8 w0h = *reinterpret_cast<const bf16x8*>(&WH[(((koff + kk) * 2 + 0) * 64 + lane) * 8]);
            bf16x8 w1h = *reinterpret_cast<const bf16x8*>(&WH[(((koff + kk) * 2 + 1) * 64 + lane) * 8]);
            bf16x8 w0l = *reinterpret_cast<const bf16x8*>(&WL[(((koff + kk) * 2 + 0) * 64 + lane) * 8]);
            bf16x8 w1l = *reinterpret_cast<const bf16x8*>(&WL[(((koff + kk) * 2 + 1) * 64 + lane) * 8]);
            a0 = __builtin_amdgcn_mfma_f32_16x16x32_bf16(fh[kk], w0h, a0, 0, 0, 0);
            a1 = __builtin_amdgcn_mfma_f32_16x16x32_bf16(fh[kk], w1h, a1, 0, 0, 0);
            a0 = __builtin_amdgcn_mfma_f32_16x16x32_bf16(fl[kk], w0h, a0, 0, 0, 0);
            a1 = __builtin_amdgcn_mfma_f32_16x16x32_bf16(fl[kk], w1h, a1, 0, 0, 0);
            a0 = __builtin_amdgcn_mfma_f32_16x16x32_bf16(fh[kk], w0l, a0, 0, 0, 0);
            a1 = __builtin_amdgcn_mfma_f32_16x16x32_bf16(fh[kk], w1l, a1, 0, 0, 0);
        }
    };

    // A: prefetch preact(0) (d_out holds preact everywhere; plain/nt loads OK)
    f32x4 pa0, pa1;
    if (isA) {
#pragma unroll
        for (int m = 0; m < 4; ++m) {
            pa0[m] = __builtin_nontemporal_load(&out[((size_t)(rowD + m) * TDIM) * HDIM + colD]);
            pa1[m] = __builtin_nontemporal_load(&out[((size_t)(rowD + m) * TDIM) * HDIM + colD + 16]);
        }
    }

    float vout[2][4];

    for (int k = 0; k <= TDIM; ++k) {
        // ============ wait at top (system-relaxed poll, zero maintenance) ============
        if (k > 0) {
            if (wv == 0) {
                const int fl = lane & 31;
                unsigned tgt;
                if (isA) tgt = (fl < NA) ? (unsigned)k
                                         : (k >= 3 ? (unsigned)(k - 2) : 0u);  // 4-slot WAR slack
                else     tgt = (unsigned)k;
                while (true) {
                    unsigned f = __hip_atomic_load(&flags[fl * 32], __ATOMIC_RELAXED,
                                                   __HIP_MEMORY_SCOPE_SYSTEM);
                    if (__all((int)(f >= tgt))) break;
                    __builtin_amdgcn_s_sleep(1);
                }
            }
            __syncthreads();
        }

        // ================= critical compute =================
        if (isA && k < TDIM) {
            const __bf16* hs = h0base + ((k + 3) & 3) * SLOT;   // h0(k-1)
            f32x4 acc0 = pa0, acc1 = pa1;
            hhalf_mfma(hs + rA * HDIM, hs + BH + rA * HDIM, 0, acc0, acc1);
            __bf16* hd = h0base + (k & 3) * SLOT;               // h0(k)
#pragma unroll
            for (int m = 0; m < 4; ++m) {
                float v0 = fast_tanh(acc0[m] + bias0);
                float v1 = fast_tanh(acc1[m] + bias1);
                stsys_bf16(&hd[(rowD + m) * HDIM + colD], v0);
                stsys_bf16(&hd[(rowD + m) * HDIM + colD + 16], v1);
                stsys_bf16(&hd[BH + (rowD + m) * HDIM + colD], v0 - (float)(__bf16)v0);
                stsys_bf16(&hd[BH + (rowD + m) * HDIM + colD + 16], v1 - (float)(__bf16)v1);
                if (k == TDIM - 1) {   // final_h layer 0 (plain; kernel-end flush)
                    out[(size_t)BDIM * TDIM * HDIM + (size_t)(rowD + m) * HDIM + colD] = v0;
                    out[(size_t)BDIM * TDIM * HDIM + (size_t)(rowD + m) * HDIM + colD + 16] = v1;
                }
            }
        } else if (!isA && k >= 1) {
            const __bf16* s0 = h0base + ((k + 3) & 3) * SLOT;   // h0(k-1)
            const __bf16* s1 = h1base + (k & 1) * SLOT;         // h1(k-2)
            f32x4 acc0 = {0.f, 0.f, 0.f, 0.f}, acc1 = {0.f, 0.f, 0.f, 0.f};
            hhalf_mfma(s1 + rA * HDIM, s1 + BH + rA * HDIM, 16, acc0, acc1);  // @Whh1
            hhalf_mfma(s0 + rA * HDIM, s0 + BH + rA * HDIM, 0, acc0, acc1);   // @Wih1
            __bf16* hd = h1base + ((k + 1) & 1) * SLOT;         // h1(k-1)
#pragma unroll
            for (int m = 0; m < 4; ++m) {
                vout[0][m] = fast_tanh(acc0[m] + bias0);
                vout[1][m] = fast_tanh(acc1[m] + bias1);
                if (k < TDIM) {
                    stsys_bf16(&hd[(rowD + m) * HDIM + colD], vout[0][m]);
                    stsys_bf16(&hd[(rowD + m) * HDIM + colD + 16], vout[1][m]);
                    stsys_bf16(&hd[BH + (rowD + m) * HDIM + colD],
                               vout[0][m] - (float)(__bf16)vout[0][m]);
                    stsys_bf16(&hd[BH + (rowD + m) * HDIM + colD + 16],
                               vout[1][m] - (float)(__bf16)vout[1][m]);
                }
            }
            if (k == TDIM) {  // last iter: store outputs inline (no arrive follows)
                const int t = k - 1;
#pragma unroll
                for (int m = 0; m < 4; ++m) {
                    __builtin_nontemporal_store(vout[0][m],
                        &out[((size_t)(rowD + m) * TDIM + t) * HDIM + colD]);
                    __builtin_nontemporal_store(vout[1][m],
                        &out[((size_t)(rowD + m) * TDIM + t) * HDIM + colD + 16]);
                    out[(size_t)BDIM * TDIM * HDIM + (size_t)(BDIM + rowD + m) * HDIM + colD] = vout[0][m];
                    out[(size_t)BDIM * TDIM * HDIM + (size_t)(BDIM + rowD + m) * HDIM + colD + 16] = vout[1][m];
                }
            }
        }

        // ================= arrive: drain stores, then flag =================
        if (k < TDIM) {
            asm volatile("s_waitcnt vmcnt(0)" ::: "memory");  // incl. untracked asm stores
            __syncthreads();
            if (tx == 0)
                __hip_atomic_store(&flags[blk * 32], (unsigned)(k + 1),
                                   __ATOMIC_RELAXED, __HIP_MEMORY_SCOPE_SYSTEM);
        }

        // ======== window: off-critical-path work ========
        if (isA) {
            if (k + 1 < TDIM) {   // prefetch preact(k+1); WAR vs B proven by flag deps
#pragma unroll
                for (int m = 0; m < 4; ++m) {
                    pa0[m] = __builtin_nontemporal_load(
                        &out[((size_t)(rowD + m) * TDIM + (k + 1)) * HDIM + colD]);
                    pa1[m] = __builtin_nontemporal_load(
                        &out[((size_t)(rowD + m) * TDIM + (k + 1)) * HDIM + colD + 16]);
                }
            }
        } else if (k >= 1 && k < TDIM) {
            const int t = k - 1;   // streaming output[b, t, :]
#pragma unroll
            for (int m = 0; m < 4; ++m) {
                __builtin_nontemporal_store(vout[0][m],
                    &out[((size_t)(rowD + m) * TDIM + t) * HDIM + colD]);
                __builtin_nontemporal_store(vout[1][m],
                    &out[((size_t)(rowD + m) * TDIM + t) * HDIM + colD + 16]);
            }
        }
    }
}

extern "C" void kernel_launch(void* const* d_in, const int* in_sizes, int n_in,
                              void* d_out, int out_size, void* d_ws, size_t ws_size,
                              hipStream_t stream) {
    (void)in_sizes; (void)n_in; (void)out_size; (void)ws_size;
    const float* x    = (const float*)d_in[0];
    const float* wih0 = (const float*)d_in[1];
    const float* whh0 = (const float*)d_in[2];
    const float* bih0 = (const float*)d_in[3];
    const float* bhh0 = (const float*)d_in[4];
    const float* wih1 = (const float*)d_in[5];
    const float* whh1 = (const float*)d_in[6];
    const float* bih1 = (const float*)d_in[7];
    const float* bhh1 = (const float*)d_in[8];
    float* out = (float*)d_out;
    unsigned char* ws = (unsigned char*)d_ws;

    // zero flags (4 KB) + h0 ring (4 slots) + h1 ring (2 slots)  [= 0.79 MB]
    hipMemsetAsync(ws, 0, 4096 + 6 * (size_t)SLOT * 2, stream);

    // Phase 1: preact0 -> d_out (all timesteps, fully parallel)
    xw0_gemm<<<dim3(8192), dim3(256), 0, stream>>>(x, wih0, out);

    // Phase 2: persistent recurrence
    void* args[] = {&whh0, &bih0, &bhh0, &wih1, &whh1, &bih1, &bhh1, &out, &ws};
    hipError_t err = hipLaunchCooperativeKernel((void*)rnn_persistent, dim3(NBLK),
                                                dim3(256), args, 0, stream);
    if (err != hipSuccess) {
        rnn_persistent<<<dim3(NBLK), dim3(256), 0, stream>>>(
            whh0, bih0, bhh0, wih1, whh1, bih1, bhh1, out, ws);
    }
}